// Round 5
// baseline (1903.788 us; speedup 1.0000x reference)
//
#include <hip/hip_runtime.h>
#include <hip/hip_bf16.h>

// ---------------------------------------------------------------------------
// VisionMamba, round 4: fused LN epilogue + bf16 activations.
// B=8, L=196, D_MODEL=192, D_INNER=384, D_STATE=16, DT_RANK=12, DEPTH=24.
//
// R4 changes:
//  - gemm_ln: out_proj/patch GEMM with fused (residual +=, LayerNorm) epilogue.
//    Block = 64 tokens x full N=192 (12 col-tiles), so LN stats reduce across
//    16 lanes in-register. Kills the separate addln kernel (122->98 launches).
//  - bf16 activation buffers (patches/hn/y): GEMM A-staging is a raw 16B copy.
//  - scan/conv unchanged from R3 (scan is 3-phase latency-free).
// ---------------------------------------------------------------------------

#define NTOK   1568   // B * L
#define DMODEL 192
#define DINNER 384
#define DSTATE 16
#define DTRANK 12
#define DEPTH  24
#define LSEQ   196
#define TCH    49     // scan time-chunk (196 = 4*49)

typedef __attribute__((ext_vector_type(8))) short short8;
typedef __attribute__((ext_vector_type(4))) float floatx4;

__device__ inline short f2bf(float f) {
    __hip_bfloat16 h = __float2bfloat16(f);
    return *reinterpret_cast<short*>(&h);
}

// ---------------- im2col for patch embed (bf16 out) ----------------
__global__ __launch_bounds__(256) void im2col(
    const float* __restrict__ x, __hip_bfloat16* __restrict__ patches)
{
    int idx = blockIdx.x * 256 + threadIdx.x;
    if (idx >= NTOK * 768) return;
    int tok = idx / 768, e = idx % 768;
    int b = tok / LSEQ, l = tok % LSEQ;
    int py = l / 14, px = l % 14;
    int ic = e >> 8, rem = e & 255, ky = rem >> 4, kx = rem & 15;
    patches[idx] = __float2bfloat16(x[((b * 3 + ic) * 224 + py * 16 + ky) * 224 + px * 16 + kx]);
}

#define LDA 40   // LDS row stride in bf16 elements (80B): uniform bank spread

// ---------------- gemm_in: xz[M,768] = hn[M,192](bf16) @ W[768,192]^T ----------------
__global__ __launch_bounds__(256) void gemm_in(
    const __hip_bfloat16* __restrict__ A, const float* __restrict__ W,
    float* __restrict__ C, int M, int N, int K)
{
    __shared__ short As[64 * LDA];
    __shared__ short Ws[64 * LDA];
    int tid = threadIdx.x;
    int m0 = blockIdx.x * 64, n0 = blockIdx.y * 64;
    int wv = tid >> 6, lane = tid & 63;
    int fm = lane & 15, q = lane >> 4;
    int row = tid >> 2, kc = (tid & 3) * 8;
    floatx4 acc[4];
#pragma unroll
    for (int nt = 0; nt < 4; ++nt) acc[nt] = (floatx4){0.f, 0.f, 0.f, 0.f};

    for (int k0 = 0; k0 < K; k0 += 32) {
        {
            int m = m0 + row;
            short8 v = {0,0,0,0,0,0,0,0};
            if (m < M) v = *(const short8*)&A[(size_t)m * K + k0 + kc];
            *(short8*)&As[row * LDA + kc] = v;
        }
        {
            int n = n0 + row;
            float4 b0 = *(const float4*)&W[(size_t)n * K + k0 + kc];
            float4 b1 = *(const float4*)&W[(size_t)n * K + k0 + kc + 4];
            short8 v;
            v[0]=f2bf(b0.x); v[1]=f2bf(b0.y); v[2]=f2bf(b0.z); v[3]=f2bf(b0.w);
            v[4]=f2bf(b1.x); v[5]=f2bf(b1.y); v[6]=f2bf(b1.z); v[7]=f2bf(b1.w);
            *(short8*)&Ws[row * LDA + kc] = v;
        }
        __syncthreads();
        short8 af = *(const short8*)&As[(wv * 16 + fm) * LDA + q * 8];
#pragma unroll
        for (int nt = 0; nt < 4; ++nt) {
            short8 bf = *(const short8*)&Ws[(nt * 16 + fm) * LDA + q * 8];
            acc[nt] = __builtin_amdgcn_mfma_f32_16x16x32_bf16(af, bf, acc[nt], 0, 0, 0);
        }
        __syncthreads();
    }
#pragma unroll
    for (int nt = 0; nt < 4; ++nt) {
        int col = n0 + nt * 16 + fm;
#pragma unroll
        for (int r = 0; r < 4; ++r) {
            int mrow = m0 + wv * 16 + q * 4 + r;
            if (mrow < M) C[(size_t)mrow * N + col] = acc[nt][r];
        }
    }
}

// ---------------- gemm_ln: C = A(bf16) @ W[192,K]^T (+bias); fused LN ----------------
// Block = 64 rows x full N=192. res = (acc? residual+C : C); residual = res;
// LN(res) -> hn (bf16) or outf (fp32, final layer). Wave w owns rows
// [16w,16w+16): per-row stats = reg sum over 12 tiles + shfl over 16 lanes.
__global__ __launch_bounds__(256) void gemm_ln(
    const __hip_bfloat16* __restrict__ A, const float* __restrict__ W,
    const float* __restrict__ bias, float* __restrict__ residual,
    __hip_bfloat16* __restrict__ hn, float* __restrict__ outf,
    const float* __restrict__ lnw, const float* __restrict__ lnb,
    int M, int K, int accumulate)
{
    __shared__ short As[64 * LDA];
    __shared__ short Ws[192 * LDA];
    __shared__ float slw[192], slb[192], sbias[192];
    int tid = threadIdx.x;
    int m0 = blockIdx.x * 64;
    int wv = tid >> 6, lane = tid & 63;
    int fm = lane & 15, q = lane >> 4;
    int row = tid >> 2, kc = (tid & 3) * 8;
    if (tid < 192) {
        slw[tid] = lnw[tid];
        slb[tid] = lnb[tid];
        sbias[tid] = bias ? bias[tid] : 0.f;
    }
    floatx4 acc[12];
#pragma unroll
    for (int nt = 0; nt < 12; ++nt) acc[nt] = (floatx4){0.f, 0.f, 0.f, 0.f};

    for (int k0 = 0; k0 < K; k0 += 32) {
        {
            int m = m0 + row;
            short8 v = {0,0,0,0,0,0,0,0};
            if (m < M) v = *(const short8*)&A[(size_t)m * K + k0 + kc];
            *(short8*)&As[row * LDA + kc] = v;
        }
#pragma unroll
        for (int j = 0; j < 3; ++j) {
            int n = row + 64 * j;
            float4 b0 = *(const float4*)&W[(size_t)n * K + k0 + kc];
            float4 b1 = *(const float4*)&W[(size_t)n * K + k0 + kc + 4];
            short8 v;
            v[0]=f2bf(b0.x); v[1]=f2bf(b0.y); v[2]=f2bf(b0.z); v[3]=f2bf(b0.w);
            v[4]=f2bf(b1.x); v[5]=f2bf(b1.y); v[6]=f2bf(b1.z); v[7]=f2bf(b1.w);
            *(short8*)&Ws[n * LDA + kc] = v;
        }
        __syncthreads();
        short8 af = *(const short8*)&As[(wv * 16 + fm) * LDA + q * 8];
#pragma unroll
        for (int nt = 0; nt < 12; ++nt) {
            short8 bf = *(const short8*)&Ws[(nt * 16 + fm) * LDA + q * 8];
            acc[nt] = __builtin_amdgcn_mfma_f32_16x16x32_bf16(af, bf, acc[nt], 0, 0, 0);
        }
        __syncthreads();
    }

    // fused epilogue: residual update + per-row LayerNorm
#pragma unroll
    for (int r = 0; r < 4; ++r) {
        int m = m0 + wv * 16 + q * 4 + r;
        bool valid = m < M;
        float v[12];
        float sum = 0.f;
#pragma unroll
        for (int nt = 0; nt < 12; ++nt) {
            int col = nt * 16 + fm;
            float t = acc[nt][r] + sbias[col];
            if (accumulate && valid) t += residual[(size_t)m * DMODEL + col];
            v[nt] = t;
            sum += t;
        }
        if (valid) {
#pragma unroll
            for (int nt = 0; nt < 12; ++nt)
                residual[(size_t)m * DMODEL + nt * 16 + fm] = v[nt];
        }
        sum += __shfl_xor(sum, 1); sum += __shfl_xor(sum, 2);
        sum += __shfl_xor(sum, 4); sum += __shfl_xor(sum, 8);
        float mean = sum * (1.f / DMODEL);
        float sq = 0.f;
#pragma unroll
        for (int nt = 0; nt < 12; ++nt) { float d = v[nt] - mean; sq += d * d; }
        sq += __shfl_xor(sq, 1); sq += __shfl_xor(sq, 2);
        sq += __shfl_xor(sq, 4); sq += __shfl_xor(sq, 8);
        float rstd = rsqrtf(sq * (1.f / DMODEL) + 1e-5f);
        if (valid) {
#pragma unroll
            for (int nt = 0; nt < 12; ++nt) {
                int col = nt * 16 + fm;
                float o = (v[nt] - mean) * rstd * slw[col] + slb[col];
                if (outf) outf[(size_t)m * DMODEL + col] = o;
                else      hn[(size_t)m * DMODEL + col] = __float2bfloat16(o);
            }
        }
    }
}

// ---------------- conv + silu + x_proj + dt(softplus) ----------------
__global__ __launch_bounds__(256) void conv_xproj_dt(
    const float* __restrict__ xz, const float* __restrict__ cw,
    const float* __restrict__ cb, const float* __restrict__ xpw,
    const float* __restrict__ dtw, const float* __restrict__ dtb,
    float* __restrict__ u, float* __restrict__ dtg, float* __restrict__ bcg)
{
    __shared__ float su[DINNER];
    __shared__ float sx[44];
    int blk = blockIdx.x;
    int b = blk / LSEQ, l = blk % LSEQ;
    int tid = threadIdx.x;
    for (int d = tid; d < DINNER; d += 256) {
        float acc = cb[d];
#pragma unroll
        for (int k = 0; k < 4; ++k) {
            int li = l - 3 + k;
            if (li >= 0) acc += xz[(size_t)(b * LSEQ + li) * 768 + d] * cw[d * 4 + k];
        }
        float sig = 1.f / (1.f + __expf(-acc));
        float val = acc * sig;
        su[d] = val;
        u[(size_t)(b * LSEQ + l) * DINNER + d] = val;
    }
    __syncthreads();
    if (tid < 176) {
        int e = tid >> 2, p = tid & 3;
        float acc = 0.f;
        const float* wr = &xpw[e * DINNER + p * 96];
        const float* ur = &su[p * 96];
#pragma unroll 8
        for (int j = 0; j < 96; ++j) acc += ur[j] * wr[j];
        acc += __shfl_xor(acc, 1);
        acc += __shfl_xor(acc, 2);
        if (p == 0) sx[e] = acc;
    }
    __syncthreads();
    for (int d = tid; d < DINNER; d += 256) {
        float acc = dtb[d];
#pragma unroll
        for (int r = 0; r < DTRANK; ++r) acc += sx[r] * dtw[d * DTRANK + r];
        float sp = (acc > 20.f) ? acc : log1pf(__expf(acc));
        dtg[(size_t)(b * LSEQ + l) * DINNER + d] = sp;
    }
    if (tid < 32) bcg[(b * LSEQ + l) * 32 + tid] = sx[DTRANK + tid];
}

// ---------------- selective scan + gating (3-phase, latency-free) ----------------
#define SPAD 272
__global__ __launch_bounds__(256) void scan_kernel(
    const float* __restrict__ u, const float* __restrict__ dtg,
    const float* __restrict__ bc, const float* __restrict__ xz,
    const float* __restrict__ Alog, const float* __restrict__ Dp,
    __hip_bfloat16* __restrict__ y)
{
    __shared__ float sdt[TCH][16];
    __shared__ float su_[TCH][16];
    __shared__ float sz_[TCH][16];
    __shared__ float sB_[TCH][16];
    __shared__ float sC_[TCH][16];
    __shared__ float sprod[TCH][SPAD];

    int b  = blockIdx.x / 24;
    int dg = blockIdx.x % 24;
    int tid = threadIdx.x;
    int s = tid & 15, dl = tid >> 4;
    int d = dg * 16 + dl;
    float Ads = -expf(Alog[d * DSTATE + s]);
    float Dd2 = Dp[dg * 16 + (tid & 15)];
    float h = 0.f;

    for (int c0 = 0; c0 < LSEQ; c0 += TCH) {
        if (tid < TCH * 4) {
            int t = tid >> 2, j4 = (tid & 3) * 4;
            size_t tok = (size_t)(b * LSEQ + c0 + t);
            *(float4*)&sdt[t][j4] = *(const float4*)&dtg[tok * DINNER + dg * 16 + j4];
            *(float4*)&su_[t][j4] = *(const float4*)&u  [tok * DINNER + dg * 16 + j4];
            *(float4*)&sz_[t][j4] = *(const float4*)&xz [tok * 768 + DINNER + dg * 16 + j4];
            *(float4*)&sB_[t][j4] = *(const float4*)&bc [tok * 32 + j4];
            *(float4*)&sC_[t][j4] = *(const float4*)&bc [tok * 32 + 16 + j4];
        }
        __syncthreads();

#pragma unroll 7
        for (int t = 0; t < TCH; ++t) {
            float dtv = sdt[t][dl];
            float uv  = su_[t][dl];
            float Bv  = sB_[t][s];
            float Cv  = sC_[t][s];
            float dA  = __expf(dtv * Ads);
            h = dA * h + (dtv * uv) * Bv;
            sprod[t][dl * 17 + s] = h * Cv;
        }
        __syncthreads();

        for (int i = tid; i < TCH * 16; i += 256) {
            int t = i >> 4, dl2 = i & 15;
            float sum = 0.f;
#pragma unroll
            for (int j = 0; j < 16; ++j) sum += sprod[t][dl2 * 17 + j];
            float uv = su_[t][dl2];
            float zv = sz_[t][dl2];
            float sig = 1.f / (1.f + __expf(-zv));
            y[(size_t)(b * LSEQ + c0 + t) * DINNER + dg * 16 + dl2] =
                __float2bfloat16((sum + uv * Dd2) * (zv * sig));
        }
        __syncthreads();
    }
}

// ---------------------------------------------------------------------------
extern "C" void kernel_launch(void* const* d_in, const int* in_sizes, int n_in,
                              void* d_out, int out_size, void* d_ws, size_t ws_size,
                              hipStream_t stream)
{
    const float* x         = (const float*)d_in[0];
    const float* pe_w      = (const float*)d_in[1];
    const float* pe_b      = (const float*)d_in[2];
    const float* norm_w    = (const float*)d_in[3];
    const float* norm_b    = (const float*)d_in[4];
    const float* in_proj_w = (const float*)d_in[5];
    const float* conv_w    = (const float*)d_in[6];
    const float* conv_b    = (const float*)d_in[7];
    const float* xproj_w   = (const float*)d_in[8];
    const float* dtproj_w  = (const float*)d_in[9];
    const float* dtproj_b  = (const float*)d_in[10];
    const float* A_log     = (const float*)d_in[11];
    const float* D_param   = (const float*)d_in[12];
    const float* outproj_w = (const float*)d_in[13];
    const float* normf_w   = (const float*)d_in[14];
    const float* normf_b   = (const float*)d_in[15];

    // workspace layout: fp32 region then bf16 region (~12.9 MB total)
    float* ws = (float*)d_ws;
    float* residual = ws;                       // 301056 f32
    float* xz       = residual + 301056;        // 1204224 f32
    float* ubuf     = xz + 1204224;             // 602112 f32
    float* dtbuf    = ubuf + 602112;            // 602112 f32
    float* bcbuf    = dtbuf + 602112;           // 50176 f32
    __hip_bfloat16* hn  = (__hip_bfloat16*)(bcbuf + 50176);  // 301056 bf16
    __hip_bfloat16* ybf = hn + 301056;                       // 602112 bf16
    __hip_bfloat16* patches = (__hip_bfloat16*)ubuf;         // alias, pre-loop only

    im2col<<<(NTOK * 768 + 255) / 256, 256, 0, stream>>>(x, patches);
    gemm_ln<<<25, 256, 0, stream>>>(
        patches, pe_w, pe_b, residual, hn, nullptr,
        norm_w, norm_b, NTOK, 768, 0);

    for (int i = 0; i < DEPTH; ++i) {
        int last = (i == DEPTH - 1);
        gemm_in<<<dim3(25, 12), 256, 0, stream>>>(
            hn, in_proj_w + (size_t)i * 768 * DMODEL, xz, NTOK, 768, DMODEL);
        conv_xproj_dt<<<NTOK, 256, 0, stream>>>(
            xz, conv_w + (size_t)i * DINNER * 4, conv_b + (size_t)i * DINNER,
            xproj_w + (size_t)i * 44 * DINNER, dtproj_w + (size_t)i * DINNER * DTRANK,
            dtproj_b + (size_t)i * DINNER, ubuf, dtbuf, bcbuf);
        scan_kernel<<<192, 256, 0, stream>>>(
            ubuf, dtbuf, bcbuf, xz, A_log + (size_t)i * DINNER * DSTATE,
            D_param + (size_t)i * DINNER, ybf);
        gemm_ln<<<25, 256, 0, stream>>>(
            ybf, outproj_w + (size_t)i * DMODEL * DINNER, nullptr, residual, hn,
            last ? (float*)d_out : nullptr,
            last ? normf_w : norm_w + (i + 1) * DMODEL,
            last ? normf_b : norm_b + (i + 1) * DMODEL,
            NTOK, DINNER, 1);
    }
}

// Round 6
// 1551.121 us; speedup vs baseline: 1.2274x; 1.2274x over previous
//
#include <hip/hip_runtime.h>
#include <hip/hip_bf16.h>

// ---------------------------------------------------------------------------
// VisionMamba, round 5: re-parallelized fused-LN GEMM.
// B=8, L=196, D_MODEL=192, D_INNER=384, D_STATE=16, DT_RANK=12, DEPTH=24.
//
// R5 change (fixes R4 regression): gemm_ln was 25 blocks (25/256 CUs busy,
// staging latency exposed). Now: 16-row M-tiles -> 98 blocks; wave w owns 3
// col-tiles; LN stats via shfl + 512B LDS cross-wave combine; k-loop software
// pipelined (prefetch k+1 into regs during MFMA of k).
// ---------------------------------------------------------------------------

#define NTOK   1568   // B * L
#define DMODEL 192
#define DINNER 384
#define DSTATE 16
#define DTRANK 12
#define DEPTH  24
#define LSEQ   196
#define TCH    49     // scan time-chunk (196 = 4*49)

typedef __attribute__((ext_vector_type(8))) short short8;
typedef __attribute__((ext_vector_type(4))) float floatx4;

__device__ inline short f2bf(float f) {
    __hip_bfloat16 h = __float2bfloat16(f);
    return *reinterpret_cast<short*>(&h);
}

// ---------------- im2col for patch embed (bf16 out) ----------------
__global__ __launch_bounds__(256) void im2col(
    const float* __restrict__ x, __hip_bfloat16* __restrict__ patches)
{
    int idx = blockIdx.x * 256 + threadIdx.x;
    if (idx >= NTOK * 768) return;
    int tok = idx / 768, e = idx % 768;
    int b = tok / LSEQ, l = tok % LSEQ;
    int py = l / 14, px = l % 14;
    int ic = e >> 8, rem = e & 255, ky = rem >> 4, kx = rem & 15;
    patches[idx] = __float2bfloat16(x[((b * 3 + ic) * 224 + py * 16 + ky) * 224 + px * 16 + kx]);
}

#define LDA 40   // LDS row stride in bf16 elements (80B): uniform bank spread

// ---------------- gemm_in: xz[M,768] = hn[M,192](bf16) @ W[768,192]^T ----------------
__global__ __launch_bounds__(256) void gemm_in(
    const __hip_bfloat16* __restrict__ A, const float* __restrict__ W,
    float* __restrict__ C, int M, int N, int K)
{
    __shared__ short As[64 * LDA];
    __shared__ short Ws[64 * LDA];
    int tid = threadIdx.x;
    int m0 = blockIdx.x * 64, n0 = blockIdx.y * 64;
    int wv = tid >> 6, lane = tid & 63;
    int fm = lane & 15, q = lane >> 4;
    int row = tid >> 2, kc = (tid & 3) * 8;
    floatx4 acc[4];
#pragma unroll
    for (int nt = 0; nt < 4; ++nt) acc[nt] = (floatx4){0.f, 0.f, 0.f, 0.f};

    for (int k0 = 0; k0 < K; k0 += 32) {
        {
            int m = m0 + row;
            short8 v = {0,0,0,0,0,0,0,0};
            if (m < M) v = *(const short8*)&A[(size_t)m * K + k0 + kc];
            *(short8*)&As[row * LDA + kc] = v;
        }
        {
            int n = n0 + row;
            float4 b0 = *(const float4*)&W[(size_t)n * K + k0 + kc];
            float4 b1 = *(const float4*)&W[(size_t)n * K + k0 + kc + 4];
            short8 v;
            v[0]=f2bf(b0.x); v[1]=f2bf(b0.y); v[2]=f2bf(b0.z); v[3]=f2bf(b0.w);
            v[4]=f2bf(b1.x); v[5]=f2bf(b1.y); v[6]=f2bf(b1.z); v[7]=f2bf(b1.w);
            *(short8*)&Ws[row * LDA + kc] = v;
        }
        __syncthreads();
        short8 af = *(const short8*)&As[(wv * 16 + fm) * LDA + q * 8];
#pragma unroll
        for (int nt = 0; nt < 4; ++nt) {
            short8 bf = *(const short8*)&Ws[(nt * 16 + fm) * LDA + q * 8];
            acc[nt] = __builtin_amdgcn_mfma_f32_16x16x32_bf16(af, bf, acc[nt], 0, 0, 0);
        }
        __syncthreads();
    }
#pragma unroll
    for (int nt = 0; nt < 4; ++nt) {
        int col = n0 + nt * 16 + fm;
#pragma unroll
        for (int r = 0; r < 4; ++r) {
            int mrow = m0 + wv * 16 + q * 4 + r;
            if (mrow < M) C[(size_t)mrow * N + col] = acc[nt][r];
        }
    }
}

// ---------------- gemm_ln: 16-row tiles, fused residual+LN epilogue ----------------
// grid = 98 (NTOK/16). 256 thr = 4 waves; wave w owns col-tiles 3w..3w+2.
// Pipelined: prefetch k+1 globals during MFMA of k.
__global__ __launch_bounds__(256) void gemm_ln(
    const __hip_bfloat16* __restrict__ A, const float* __restrict__ W,
    const float* __restrict__ bias, float* __restrict__ residual,
    __hip_bfloat16* __restrict__ hn, float* __restrict__ outf,
    const float* __restrict__ lnw, const float* __restrict__ lnb,
    int K, int accumulate)
{
    __shared__ short As[16 * LDA];
    __shared__ short Ws[192 * LDA];
    __shared__ float slw[192], slb[192], sbias[192];
    __shared__ float sS1[4][16], sS2[4][16];
    int tid = threadIdx.x;
    int m0 = blockIdx.x * 16;
    int wv = tid >> 6, lane = tid & 63;
    int fm = lane & 15, q = lane >> 4;
    int wrow = tid >> 2, kc = (tid & 3) * 8;
    if (tid < 192) {
        slw[tid] = lnw[tid];
        slb[tid] = lnb[tid];
        sbias[tid] = bias ? bias[tid] : 0.f;
    }
    floatx4 acc[3];
#pragma unroll
    for (int j = 0; j < 3; ++j) acc[j] = (floatx4){0.f, 0.f, 0.f, 0.f};

    // prologue: load k0=0 into regs
    short8 aR = {0,0,0,0,0,0,0,0};
    float4 b0[3], b1[3];
    if (tid < 64) aR = *(const short8*)&A[(size_t)(m0 + (tid >> 2)) * K + kc];
#pragma unroll
    for (int j = 0; j < 3; ++j) {
        int n = wrow + 64 * j;
        b0[j] = *(const float4*)&W[(size_t)n * K + kc];
        b1[j] = *(const float4*)&W[(size_t)n * K + kc + 4];
    }

    for (int k0 = 0; k0 < K; k0 += 32) {
        // write staged regs (data for step k0) to LDS
        if (tid < 64) *(short8*)&As[(tid >> 2) * LDA + kc] = aR;
#pragma unroll
        for (int j = 0; j < 3; ++j) {
            int n = wrow + 64 * j;
            short8 v;
            v[0]=f2bf(b0[j].x); v[1]=f2bf(b0[j].y); v[2]=f2bf(b0[j].z); v[3]=f2bf(b0[j].w);
            v[4]=f2bf(b1[j].x); v[5]=f2bf(b1[j].y); v[6]=f2bf(b1[j].z); v[7]=f2bf(b1[j].w);
            *(short8*)&Ws[n * LDA + kc] = v;
        }
        __syncthreads();
        // prefetch step k0+32
        int kn = k0 + 32;
        if (kn < K) {
            if (tid < 64) aR = *(const short8*)&A[(size_t)(m0 + (tid >> 2)) * K + kn + kc];
#pragma unroll
            for (int j = 0; j < 3; ++j) {
                int n = wrow + 64 * j;
                b0[j] = *(const float4*)&W[(size_t)n * K + kn + kc];
                b1[j] = *(const float4*)&W[(size_t)n * K + kn + kc + 4];
            }
        }
        // MFMA on step k0
        short8 af = *(const short8*)&As[fm * LDA + q * 8];
#pragma unroll
        for (int j = 0; j < 3; ++j) {
            int ct = wv * 3 + j;
            short8 bf = *(const short8*)&Ws[(ct * 16 + fm) * LDA + q * 8];
            acc[j] = __builtin_amdgcn_mfma_f32_16x16x32_bf16(af, bf, acc[j], 0, 0, 0);
        }
        __syncthreads();
    }

    // ---- fused epilogue: residual += C(+bias); LN(residual) -> hn/outf ----
    float v[3][4];
#pragma unroll
    for (int r = 0; r < 4; ++r) {
        int m = m0 + q * 4 + r;
#pragma unroll
        for (int j = 0; j < 3; ++j) {
            int col = (wv * 3 + j) * 16 + fm;
            float t = acc[j][r] + sbias[col];
            if (accumulate) t += residual[(size_t)m * DMODEL + col];
            v[j][r] = t;
        }
    }
#pragma unroll
    for (int r = 0; r < 4; ++r) {
        int m = m0 + q * 4 + r;
#pragma unroll
        for (int j = 0; j < 3; ++j)
            residual[(size_t)m * DMODEL + (wv * 3 + j) * 16 + fm] = v[j][r];
    }
#pragma unroll
    for (int r = 0; r < 4; ++r) {
        float s1 = v[0][r] + v[1][r] + v[2][r];
        float s2 = v[0][r]*v[0][r] + v[1][r]*v[1][r] + v[2][r]*v[2][r];
        s1 += __shfl_xor(s1, 1); s2 += __shfl_xor(s2, 1);
        s1 += __shfl_xor(s1, 2); s2 += __shfl_xor(s2, 2);
        s1 += __shfl_xor(s1, 4); s2 += __shfl_xor(s2, 4);
        s1 += __shfl_xor(s1, 8); s2 += __shfl_xor(s2, 8);
        if (fm == 0) { sS1[wv][q * 4 + r] = s1; sS2[wv][q * 4 + r] = s2; }
    }
    __syncthreads();
#pragma unroll
    for (int r = 0; r < 4; ++r) {
        int row = q * 4 + r;
        int m = m0 + row;
        float S1 = sS1[0][row] + sS1[1][row] + sS1[2][row] + sS1[3][row];
        float S2 = sS2[0][row] + sS2[1][row] + sS2[2][row] + sS2[3][row];
        float mean = S1 * (1.f / DMODEL);
        float var  = S2 * (1.f / DMODEL) - mean * mean;
        float rstd = rsqrtf(var + 1e-5f);
#pragma unroll
        for (int j = 0; j < 3; ++j) {
            int col = (wv * 3 + j) * 16 + fm;
            float o = (v[j][r] - mean) * rstd * slw[col] + slb[col];
            if (outf) outf[(size_t)m * DMODEL + col] = o;
            else      hn[(size_t)m * DMODEL + col] = __float2bfloat16(o);
        }
    }
}

// ---------------- conv + silu + x_proj + dt(softplus) ----------------
__global__ __launch_bounds__(256) void conv_xproj_dt(
    const float* __restrict__ xz, const float* __restrict__ cw,
    const float* __restrict__ cb, const float* __restrict__ xpw,
    const float* __restrict__ dtw, const float* __restrict__ dtb,
    float* __restrict__ u, float* __restrict__ dtg, float* __restrict__ bcg)
{
    __shared__ float su[DINNER];
    __shared__ float sx[44];
    int blk = blockIdx.x;
    int b = blk / LSEQ, l = blk % LSEQ;
    int tid = threadIdx.x;
    for (int d = tid; d < DINNER; d += 256) {
        float acc = cb[d];
#pragma unroll
        for (int k = 0; k < 4; ++k) {
            int li = l - 3 + k;
            if (li >= 0) acc += xz[(size_t)(b * LSEQ + li) * 768 + d] * cw[d * 4 + k];
        }
        float sig = 1.f / (1.f + __expf(-acc));
        float val = acc * sig;
        su[d] = val;
        u[(size_t)(b * LSEQ + l) * DINNER + d] = val;
    }
    __syncthreads();
    if (tid < 176) {
        int e = tid >> 2, p = tid & 3;
        float acc = 0.f;
        const float* wr = &xpw[e * DINNER + p * 96];
        const float* ur = &su[p * 96];
#pragma unroll 8
        for (int j = 0; j < 96; ++j) acc += ur[j] * wr[j];
        acc += __shfl_xor(acc, 1);
        acc += __shfl_xor(acc, 2);
        if (p == 0) sx[e] = acc;
    }
    __syncthreads();
    for (int d = tid; d < DINNER; d += 256) {
        float acc = dtb[d];
#pragma unroll
        for (int r = 0; r < DTRANK; ++r) acc += sx[r] * dtw[d * DTRANK + r];
        float sp = (acc > 20.f) ? acc : log1pf(__expf(acc));
        dtg[(size_t)(b * LSEQ + l) * DINNER + d] = sp;
    }
    if (tid < 32) bcg[(b * LSEQ + l) * 32 + tid] = sx[DTRANK + tid];
}

// ---------------- selective scan + gating (3-phase, latency-free) ----------------
#define SPAD 272
__global__ __launch_bounds__(256) void scan_kernel(
    const float* __restrict__ u, const float* __restrict__ dtg,
    const float* __restrict__ bc, const float* __restrict__ xz,
    const float* __restrict__ Alog, const float* __restrict__ Dp,
    __hip_bfloat16* __restrict__ y)
{
    __shared__ float sdt[TCH][16];
    __shared__ float su_[TCH][16];
    __shared__ float sz_[TCH][16];
    __shared__ float sB_[TCH][16];
    __shared__ float sC_[TCH][16];
    __shared__ float sprod[TCH][SPAD];

    int b  = blockIdx.x / 24;
    int dg = blockIdx.x % 24;
    int tid = threadIdx.x;
    int s = tid & 15, dl = tid >> 4;
    int d = dg * 16 + dl;
    float Ads = -expf(Alog[d * DSTATE + s]);
    float Dd2 = Dp[dg * 16 + (tid & 15)];
    float h = 0.f;

    for (int c0 = 0; c0 < LSEQ; c0 += TCH) {
        if (tid < TCH * 4) {
            int t = tid >> 2, j4 = (tid & 3) * 4;
            size_t tok = (size_t)(b * LSEQ + c0 + t);
            *(float4*)&sdt[t][j4] = *(const float4*)&dtg[tok * DINNER + dg * 16 + j4];
            *(float4*)&su_[t][j4] = *(const float4*)&u  [tok * DINNER + dg * 16 + j4];
            *(float4*)&sz_[t][j4] = *(const float4*)&xz [tok * 768 + DINNER + dg * 16 + j4];
            *(float4*)&sB_[t][j4] = *(const float4*)&bc [tok * 32 + j4];
            *(float4*)&sC_[t][j4] = *(const float4*)&bc [tok * 32 + 16 + j4];
        }
        __syncthreads();

#pragma unroll 7
        for (int t = 0; t < TCH; ++t) {
            float dtv = sdt[t][dl];
            float uv  = su_[t][dl];
            float Bv  = sB_[t][s];
            float Cv  = sC_[t][s];
            float dA  = __expf(dtv * Ads);
            h = dA * h + (dtv * uv) * Bv;
            sprod[t][dl * 17 + s] = h * Cv;
        }
        __syncthreads();

        for (int i = tid; i < TCH * 16; i += 256) {
            int t = i >> 4, dl2 = i & 15;
            float sum = 0.f;
#pragma unroll
            for (int j = 0; j < 16; ++j) sum += sprod[t][dl2 * 17 + j];
            float uv = su_[t][dl2];
            float zv = sz_[t][dl2];
            float sig = 1.f / (1.f + __expf(-zv));
            y[(size_t)(b * LSEQ + c0 + t) * DINNER + dg * 16 + dl2] =
                __float2bfloat16((sum + uv * Dd2) * (zv * sig));
        }
        __syncthreads();
    }
}

// ---------------------------------------------------------------------------
extern "C" void kernel_launch(void* const* d_in, const int* in_sizes, int n_in,
                              void* d_out, int out_size, void* d_ws, size_t ws_size,
                              hipStream_t stream)
{
    const float* x         = (const float*)d_in[0];
    const float* pe_w      = (const float*)d_in[1];
    const float* pe_b      = (const float*)d_in[2];
    const float* norm_w    = (const float*)d_in[3];
    const float* norm_b    = (const float*)d_in[4];
    const float* in_proj_w = (const float*)d_in[5];
    const float* conv_w    = (const float*)d_in[6];
    const float* conv_b    = (const float*)d_in[7];
    const float* xproj_w   = (const float*)d_in[8];
    const float* dtproj_w  = (const float*)d_in[9];
    const float* dtproj_b  = (const float*)d_in[10];
    const float* A_log     = (const float*)d_in[11];
    const float* D_param   = (const float*)d_in[12];
    const float* outproj_w = (const float*)d_in[13];
    const float* normf_w   = (const float*)d_in[14];
    const float* normf_b   = (const float*)d_in[15];

    float* ws = (float*)d_ws;
    float* residual = ws;                       // 301056 f32
    float* xz       = residual + 301056;        // 1204224 f32
    float* ubuf     = xz + 1204224;             // 602112 f32
    float* dtbuf    = ubuf + 602112;            // 602112 f32
    float* bcbuf    = dtbuf + 602112;           // 50176 f32
    __hip_bfloat16* hn  = (__hip_bfloat16*)(bcbuf + 50176);  // 301056 bf16
    __hip_bfloat16* ybf = hn + 301056;                       // 602112 bf16
    __hip_bfloat16* patches = (__hip_bfloat16*)ubuf;         // alias, pre-loop only

    im2col<<<(NTOK * 768 + 255) / 256, 256, 0, stream>>>(x, patches);
    gemm_ln<<<98, 256, 0, stream>>>(
        patches, pe_w, pe_b, residual, hn, nullptr,
        norm_w, norm_b, 768, 0);

    for (int i = 0; i < DEPTH; ++i) {
        int last = (i == DEPTH - 1);
        gemm_in<<<dim3(25, 12), 256, 0, stream>>>(
            hn, in_proj_w + (size_t)i * 768 * DMODEL, xz, NTOK, 768, DMODEL);
        conv_xproj_dt<<<NTOK, 256, 0, stream>>>(
            xz, conv_w + (size_t)i * DINNER * 4, conv_b + (size_t)i * DINNER,
            xproj_w + (size_t)i * 44 * DINNER, dtproj_w + (size_t)i * DINNER * DTRANK,
            dtproj_b + (size_t)i * DINNER, ubuf, dtbuf, bcbuf);
        scan_kernel<<<192, 256, 0, stream>>>(
            ubuf, dtbuf, bcbuf, xz, A_log + (size_t)i * DINNER * DSTATE,
            D_param + (size_t)i * DINNER, ybf);
        gemm_ln<<<98, 256, 0, stream>>>(
            ybf, outproj_w + (size_t)i * DMODEL * DINNER, nullptr, residual, hn,
            last ? (float*)d_out : nullptr,
            last ? normf_w : norm_w + (i + 1) * DMODEL,
            last ? normf_b : norm_b + (i + 1) * DMODEL,
            DINNER, 1);
    }
}